// Round 9
// baseline (101.406 us; speedup 1.0000x reference)
//
#include <hip/hip_runtime.h>
#include <cstdint>

typedef __bf16 bf16x8 __attribute__((ext_vector_type(8)));
typedef float floatx4 __attribute__((ext_vector_type(4)));

// M = 4096 rows, C(K) = 256. ROUND 9 = ROUND 8 RERUN (container infra
// failure, no data). Register-pressure fix + epilogue probe.
// R7 proved: pure fragment loads = 4.6 us (55 TB/s, L2-resident), so the
// ~40 us GEMM mystery is a loads+MFMA interaction. Theory: the (256,4)
// 128-VGPR cap forced load->vmcnt(0)->mfma serialization (R3's VGPR=128
// exactly-at-cap corroborates). Fix: (256,2) -> 256 VGPR budget + explicit
// two-set register double-buffer (acc 64 + 2x32 frags + temps ~ 175 regs,
// no spill). One probe_mfma (= gemm_wave2 minus epilogue) appended so
// gemm' - probe isolates the epilogue cost in the same bench.
//
// Staged layout: Xs[rb(32)][s(4)][kk(2)][rowhi(8)][quad(4)][rowlo(16)][8 bf16]
// holding X[row = rb*128+rowhi*16+rowlo][k = s*64+kk*32+quad*8+j].
// Fragment for 16-row group rowhi at K-step (s,kk): lane reads 16 B at
//   Xs + rb*32768 + (s*1024 + kk*512 + rowhi*64 + lane)*8.

#define OFF_X     (0u)
#define OFF_Y     (2u*1024*1024)
#define OFF_PMAX  (4u*1024*1024)
#define OFF_PSUM  (5u*1024*1024)
#define OFF_DIAG  (6u*1024*1024)
#define OFF_LPART (OFF_DIAG + 16384u)
#define OFF_CPART (OFF_LPART + 256u)
#define OFF_CNT   (OFF_CPART + 256u)   // cnt[0]: combine arrival counter
#define OFF_SCR   (8u*1024*1024)       // probe sink (never read)

// ---------------------------------------------------------------------------
// K0: fp32 -> staged bf16. One block per (b,n) slab. Block 0 zeroes cnt.
// ---------------------------------------------------------------------------
__global__ __launch_bounds__(256) void transpose_stage(
    const float* __restrict__ pred, const float* __restrict__ gt,
    unsigned short* __restrict__ Xs, unsigned short* __restrict__ Ys,
    int* __restrict__ cnt) {
  int blk = blockIdx.x;
  const int t = threadIdx.x;
  if (blk == 0 && t < 33) cnt[t] = 0;
  const float* src;
  unsigned short* dst;
  int slab;
  if (blk < 256) { src = pred; dst = Xs; slab = blk; }
  else           { src = gt;   dst = Ys; slab = blk - 256; }
  const float* sb = src + slab * 4096;
  const int rb = slab >> 3, rowhi = slab & 7;
  #pragma unroll
  for (int half = 0; half < 2; ++half) {
    int c_ = half * 256 + t;                 // chunk id within slab, 0..511
    int rowlo = c_ & 15;
    int quad  = (c_ >> 4) & 3;
    int kk    = (c_ >> 6) & 1;
    int s     = c_ >> 7;
    int k0 = s * 64 + kk * 32 + quad * 8;
    unsigned int packed[4];
    #pragma unroll
    for (int jj = 0; jj < 4; ++jj) {
      unsigned int lohi[2];
      #pragma unroll
      for (int e = 0; e < 2; ++e) {
        float f = sb[(k0 + jj * 2 + e) * 16 + rowlo];
        unsigned int u = __float_as_uint(f);
        lohi[e] = (u + 0x7FFFu + ((u >> 16) & 1u)) >> 16;   // RNE -> bf16
      }
      packed[jj] = lohi[0] | (lohi[1] << 16);
    }
    unsigned short* o = dst + rb * 32768 +
        (unsigned)(s * 1024 + kk * 512 + rowhi * 64 + quad * 16 + rowlo) * 8;
    uint4 v; v.x = packed[0]; v.y = packed[1]; v.z = packed[2]; v.w = packed[3];
    *reinterpret_cast<uint4*>(o) = v;
  }
}

// Common per-wave mapping + K-loop macros (shared by gemm_wave2 / probe_mfma).
// Two fragment sets (a0/b0, a1/b1): loads for step k+1 issue BEFORE the
// MFMAs of step k, so ~8 loads stay in flight throughout.
#define WAVE_MAP()                                                           \
  const int t = threadIdx.x;                                                 \
  const int wv = t >> 6, lane = t & 63;                                      \
  const int b = blockIdx.x;                                                  \
  const int xcd = b & 7, slot = b >> 3;                                      \
  const int rowb = ((xcd >> 1) << 4) | (slot & 15);                          \
  const int colb = ((xcd & 1) << 3) | (slot >> 4);                           \
  const int hh = rowb & 1, ch = wv & 1;                                      \
  const unsigned short* Ab = Xs + (rowb >> 1) * 32768 + (unsigned)lane * 8;  \
  const unsigned short* Bb = Ys + ((colb << 1) | (wv >> 1)) * 32768 +        \
                             (unsigned)lane * 8;

#define KOFF(KS) ((unsigned)((((KS) >> 1) * 1024 + ((KS)&1) * 512)) * 8)

#define LOADF(AR, BR, KS) do {                                               \
    _Pragma("unroll") for (int fr = 0; fr < 4; ++fr)                         \
      AR[fr] = *reinterpret_cast<const bf16x8*>(                             \
          Ab + KOFF(KS) + (unsigned)((hh * 4 + fr) * 64) * 8);               \
    _Pragma("unroll") for (int fc = 0; fc < 4; ++fc)                         \
      BR[fc] = *reinterpret_cast<const bf16x8*>(                             \
          Bb + KOFF(KS) + (unsigned)((ch * 4 + fc) * 64) * 8);               \
  } while (0)

#define MM(AR, BR) do {                                                      \
    _Pragma("unroll") for (int fr = 0; fr < 4; ++fr)                         \
      _Pragma("unroll") for (int fc = 0; fc < 4; ++fc)                       \
        acc[fr][fc] = __builtin_amdgcn_mfma_f32_16x16x32_bf16(               \
            AR[fr], BR[fc], acc[fr][fc], 0, 0, 0);                           \
  } while (0)

#define KLOOP_DBUF() do {                                                    \
    bf16x8 a0[4], b0[4], a1[4], b1[4];                                       \
    LOADF(a0, b0, 0);                                                        \
    LOADF(a1, b1, 1); MM(a0, b0);                                            \
    LOADF(a0, b0, 2); MM(a1, b1);                                            \
    LOADF(a1, b1, 3); MM(a0, b0);                                            \
    LOADF(a0, b0, 4); MM(a1, b1);                                            \
    LOADF(a1, b1, 5); MM(a0, b0);                                            \
    LOADF(a0, b0, 6); MM(a1, b1);                                            \
    LOADF(a1, b1, 7); MM(a0, b0);                                            \
    MM(a1, b1);                                                              \
  } while (0)

// ---------------------------------------------------------------------------
// K1: per-wave 64x64 GEMM tile, no LDS, no barriers; 256-VGPR budget
// ((256,2): 2 waves/SIMD min) + explicit register double-buffer. Epilogue
// identical to R6 (per-row max/sum-exp partials + diag).
// ---------------------------------------------------------------------------
__global__ __launch_bounds__(256, 2) void gemm_wave2(
    const unsigned short* __restrict__ Xs, const unsigned short* __restrict__ Ys,
    float* __restrict__ pmax, float* __restrict__ psum, float* __restrict__ diag) {
  WAVE_MAP();
  floatx4 acc[4][4];
  const floatx4 zero = {0.f, 0.f, 0.f, 0.f};
  #pragma unroll
  for (int i = 0; i < 4; ++i)
    #pragma unroll
    for (int j = 0; j < 4; ++j) acc[i][j] = zero;

  KLOOP_DBUF();

  const int quad = lane >> 4, lc = lane & 15;

  if (colb * 4 + wv == rowb) {
    #pragma unroll
    for (int fr = 0; fr < 4; ++fr)
      #pragma unroll
      for (int r = 0; r < 4; ++r)
        if (lc == quad * 4 + r)
          diag[rowb * 64 + fr * 16 + lc] = acc[fr][fr][r];
  }

  #pragma unroll
  for (int fr = 0; fr < 4; ++fr) {
    #pragma unroll
    for (int r = 0; r < 4; ++r) {
      float v0 = acc[fr][0][r], v1 = acc[fr][1][r];
      float v2 = acc[fr][2][r], v3 = acc[fr][3][r];
      float m = fmaxf(fmaxf(v0, v1), fmaxf(v2, v3));
      #pragma unroll
      for (int sh = 1; sh < 16; sh <<= 1) m = fmaxf(m, __shfl_xor(m, sh, 64));
      float ss = __expf(v0 - m) + __expf(v1 - m) +
                 __expf(v2 - m) + __expf(v3 - m);
      #pragma unroll
      for (int sh = 1; sh < 16; sh <<= 1) ss += __shfl_xor(ss, sh, 64);
      if (lc == 0) {
        int grow = rowb * 64 + fr * 16 + quad * 4 + r;
        int p = grow * 64 + colb * 4 + wv;
        pmax[p] = m; psum[p] = ss;
      }
    }
  }
}

// ---------------------------------------------------------------------------
// PROBE (diagnostic, x1): gemm_wave2 minus epilogue. Same mapping, same
// dbuf K-loop, acc folded to one float4/lane and stored coalesced (4 MB) so
// the MFMAs can't be DCE'd. gemm' - probe = epilogue cost.
// ---------------------------------------------------------------------------
__global__ __launch_bounds__(256, 2) void probe_mfma(
    const unsigned short* __restrict__ Xs, const unsigned short* __restrict__ Ys,
    float* __restrict__ scratch) {
  WAVE_MAP();
  floatx4 acc[4][4];
  const floatx4 zero = {0.f, 0.f, 0.f, 0.f};
  #pragma unroll
  for (int i = 0; i < 4; ++i)
    #pragma unroll
    for (int j = 0; j < 4; ++j) acc[i][j] = zero;

  KLOOP_DBUF();

  floatx4 cs = zero;
  #pragma unroll
  for (int fr = 0; fr < 4; ++fr)
    #pragma unroll
    for (int fc = 0; fc < 4; ++fc) cs += acc[fr][fc];
  *reinterpret_cast<floatx4*>(scratch + (size_t)(b * 256 + t) * 4) = cs;
}

// ---------------------------------------------------------------------------
// K2: per-row combine + fused finalize (R6, unchanged).
// ---------------------------------------------------------------------------
__global__ __launch_bounds__(256) void combine_rows(
    const float* __restrict__ pmax, const float* __restrict__ psum,
    const float* __restrict__ diag,
    float* __restrict__ lpart, float* __restrict__ cpart,
    int* __restrict__ cnt, float* __restrict__ out) {
  int row = blockIdx.x * 256 + threadIdx.x;
  const float* pm = pmax + row * 64;
  const float* ps = psum + row * 64;
  float M = -3.4e38f;
  #pragma unroll 8
  for (int b = 0; b < 64; ++b) M = fmaxf(M, pm[b]);
  float S = 0.f;
  #pragma unroll 8
  for (int b = 0; b < 64; ++b) S += ps[b] * __expf(pm[b] - M);
  float d = diag[row];
  float lossr = logf(S) + M - d;
  float corr = (d == M) ? 1.f : 0.f;
  #pragma unroll
  for (int sh = 1; sh < 64; sh <<= 1) {
    lossr += __shfl_xor(lossr, sh, 64);
    corr  += __shfl_xor(corr,  sh, 64);
  }
  __shared__ float ls[4], cs[4];
  int wave = threadIdx.x >> 6, lane = threadIdx.x & 63;
  if (lane == 0) { ls[wave] = lossr; cs[wave] = corr; }
  __syncthreads();
  if (threadIdx.x == 0) {
    lpart[blockIdx.x] = ls[0] + ls[1] + ls[2] + ls[3];
    cpart[blockIdx.x] = cs[0] + cs[1] + cs[2] + cs[3];
    __threadfence();                     // release per-block partial
    if (atomicAdd(cnt, 1) == 15) {       // last arriver finalizes
      __threadfence();                   // acquire all partials
      float L = 0.f, C = 0.f;
      for (int i = 0; i < 16; ++i) { L += lpart[i]; C += cpart[i]; }
      out[0] = L * (1.f / 4096.f);
      out[1] = C * (100.f / 4096.f);
    }
  }
}

extern "C" void kernel_launch(void* const* d_in, const int* in_sizes, int n_in,
                              void* d_out, int out_size, void* d_ws, size_t ws_size,
                              hipStream_t stream) {
  const float* pred = (const float*)d_in[0];
  const float* gt   = (const float*)d_in[1];
  char* w = (char*)d_ws;
  unsigned short* Xbf = (unsigned short*)(w + OFF_X);
  unsigned short* Ybf = (unsigned short*)(w + OFF_Y);
  float* pmax  = (float*)(w + OFF_PMAX);
  float* psum  = (float*)(w + OFF_PSUM);
  float* diag  = (float*)(w + OFF_DIAG);
  float* lpart = (float*)(w + OFF_LPART);
  float* cpart = (float*)(w + OFF_CPART);
  int*   cnt   = (int*)(w + OFF_CNT);
  float* scr   = (float*)(w + OFF_SCR);
  float* out   = (float*)d_out;

  transpose_stage<<<512, 256, 0, stream>>>(pred, gt, Xbf, Ybf, cnt);
  gemm_wave2<<<1024, 256, 0, stream>>>(Xbf, Ybf, pmax, psum, diag);
  combine_rows<<<16, 256, 0, stream>>>(pmax, psum, diag, lpart, cpart, cnt, out);
  probe_mfma<<<1024, 256, 0, stream>>>(Xbf, Ybf, scr);   // diagnostic
}